// Round 12
// baseline (329.047 us; speedup 1.0000x reference)
//
#include <hip/hip_runtime.h>
#include <hip/hip_bf16.h>
#include <stdint.h>

// ---------------- problem constants ----------------
#define EDGES   300000
#define NLIT    50000
#define NGRAPH  4
#define EPG     75000          // edges per graph (contiguous)
#define HDIM    64

// ws layout (bytes)
#define OFF_HL2C   0
#define OFF_HC2L   38400000
#define OFF_AGG    76800000
#define OFF_WT     89600000
#define OFF_ROACC  89681920
#define OFF_CNT    89682944
#define OFF_CSROFF 89882944
#define OFF_CURSOR 90082948
#define OFF_EIDX   90282948
#define OFF_BSUM   91482948
#define OFF_BBASE  91484000

// wT global layout: 10 "units", each [64 rows=out][64 cols=in] bf16 (4096 elems),
// stored PRE-SWIZZLED: element (u,row,col) at u*4096 + row*64 + (col ^ ((row&7)<<3)).
// u0-2: msglT ; u3: merge0T cols 0-63 (m part) ; u4: merge0T cols 64-127 (h part)
// u5-6: mergeRT ; u7-9: msgcT
#define WT_TOTAL    40960
#define WT_CLS_ELEM 28672      // element offset of clause units (u7)

#define LIT_WBYTES (7 * 8192)   // 57344
#define CLS_WBYTES (3 * 8192)   // 24576 (clause weights region in phase 2)
#define EPB2       256          // edges per block (8 waves x 32)
#define GRID_EDGE  ((EDGES + EPB2 - 1) / EPB2)   // 1172

#define SCAN_BLOCKS ((NLIT + 255) / 256)   // 196

typedef __attribute__((ext_vector_type(8)))  short          s16x8;
typedef __attribute__((ext_vector_type(8)))  unsigned short u16x8;
typedef __attribute__((ext_vector_type(4)))  unsigned short u16x4;
typedef __attribute__((ext_vector_type(4)))  float          f32x4;
typedef __attribute__((ext_vector_type(16))) float          f32x16;

__device__ __forceinline__ f32x16 mfma32(s16x8 a, s16x8 b, f32x16 c) {
    return __builtin_amdgcn_mfma_f32_32x32x16_bf16(a, b, c, 0, 0, 0);
}
__device__ __forceinline__ float bf2f(unsigned short s) {
    union { unsigned int u; float f; } v; v.u = ((unsigned int)s) << 16; return v.f;
}
__device__ __forceinline__ unsigned short f2bf(float f) {
    union { __hip_bfloat16 b; unsigned short s; } v;
    v.b = __float2bfloat16(f);
    return v.s;
}
__device__ __forceinline__ unsigned pk2(float a, float b) {
    return (unsigned)f2bf(a) | ((unsigned)f2bf(b) << 16);
}

// in-register C->B relayout, 2 bpermutes/kb (select-before-permute), HW-verified
template<bool RELU>
__device__ __forceinline__ void relayout32(f32x16 (&acc)[2], s16x8 (&bout)[4],
                                           int bpidx, int hi)
{
    if (RELU) {
#pragma unroll
        for (int t = 0; t < 2; ++t)
#pragma unroll
            for (int i = 0; i < 16; ++i) acc[t][i] = fmaxf(acc[t][i], 0.f);
    }
#pragma unroll
    for (int kb = 0; kb < 4; ++kb) {
        int m0 = 2 * kb, m1 = 2 * kb + 1;
        int t0 = m0 >> 2, g0 = m0 & 3, t1 = m1 >> 2, g1 = m1 & 3;
        unsigned A0 = pk2(acc[t0][4 * g0 + 0], acc[t0][4 * g0 + 1]);
        unsigned A1 = pk2(acc[t0][4 * g0 + 2], acc[t0][4 * g0 + 3]);
        unsigned B0 = pk2(acc[t1][4 * g1 + 0], acc[t1][4 * g1 + 1]);
        unsigned B1 = pk2(acc[t1][4 * g1 + 2], acc[t1][4 * g1 + 3]);
        unsigned s0 = hi ? A0 : B0;
        unsigned s1 = hi ? A1 : B1;
        unsigned p0 = (unsigned)__builtin_amdgcn_ds_bpermute(bpidx, (int)s0);
        unsigned p1 = (unsigned)__builtin_amdgcn_ds_bpermute(bpidx, (int)s1);
        union { unsigned w[4]; s16x8 v; } u;
        u.w[0] = hi ? p0 : A0;
        u.w[1] = hi ? p1 : A1;
        u.w[2] = hi ? B0 : p0;
        u.w[3] = hi ? B1 : p1;
        bout[kb] = u.v;
    }
}

__device__ __forceinline__ void store32(const f32x16 (&acc)[2],
                                        unsigned short* __restrict__ dst, int hi)
{
#pragma unroll
    for (int t = 0; t < 2; ++t)
#pragma unroll
        for (int g = 0; g < 4; ++g) {
            u16x4 p;
#pragma unroll
            for (int r = 0; r < 4; ++r) p[r] = f2bf(acc[t][4 * g + r]);
            *(u16x4*)(dst + 32 * t + 8 * g + 4 * hi) = p;
        }
}

// one 64->64 layer, weights in swizzled LDS unit, bias in LDS
__device__ __forceinline__ void layer32(const char* __restrict__ unitBase,
                                        const float* __restrict__ biasL,
                                        const s16x8 (&bin)[4], f32x16 (&acc)[2],
                                        int eL, int hi)
{
#pragma unroll
    for (int t = 0; t < 2; ++t)
#pragma unroll
        for (int g = 0; g < 4; ++g) {
            f32x4 bv = *(const f32x4*)(biasL + 32 * t + 8 * g + 4 * hi);
#pragma unroll
            for (int r = 0; r < 4; ++r) acc[t][4 * g + r] = bv[r];
        }
#pragma unroll
    for (int kb = 0; kb < 4; ++kb)
#pragma unroll
        for (int t = 0; t < 2; ++t) {
            int row = 32 * t + eL;
            s16x8 a = *(const s16x8*)(unitBase + row * 128 +
                                      ((32 * kb + 16 * hi) ^ ((row & 7) << 4)));
            acc[t] = mfma32(a, bin[kb], acc[t]);
        }
}

// layer with A-fragments straight from pre-swizzled GLOBAL wT (fixup path)
__device__ __forceinline__ void layer32g(const unsigned short* __restrict__ unit,
                                         const float* __restrict__ biasG,
                                         const s16x8 (&bin)[4], f32x16 (&acc)[2],
                                         int eL, int hi)
{
#pragma unroll
    for (int t = 0; t < 2; ++t)
#pragma unroll
        for (int g = 0; g < 4; ++g) {
            f32x4 bv = *(const f32x4*)(biasG + 32 * t + 8 * g + 4 * hi);
#pragma unroll
            for (int r = 0; r < 4; ++r) acc[t][4 * g + r] = bv[r];
        }
#pragma unroll
    for (int kb = 0; kb < 4; ++kb)
#pragma unroll
        for (int t = 0; t < 2; ++t) {
            int row = 32 * t + eL;
            s16x8 a = *(const s16x8*)(unit + row * 64 +
                                      ((32 * kb + 16 * hi) ^ ((row & 7) << 3)));
            acc[t] = mfma32(a, bin[kb], acc[t]);
        }
}

// -------- transpose + bf16 + PRE-SWIZZLE all round weights into unit layout --------
__global__ __launch_bounds__(256) void prep_weights(
    const float* __restrict__ msgl_W, const float* __restrict__ merge_W0,
    const float* __restrict__ merge_Wr, const float* __restrict__ msgc_W,
    unsigned short* __restrict__ wT)
{
    int gid = blockIdx.x * 256 + threadIdx.x;
    if (gid >= WT_TOTAL) return;
    int unit = gid >> 12;
    int o = (gid >> 6) & 63;              // row = out
    int csw = gid & 63;
    int i = csw ^ ((o & 7) << 3);         // col = in (un-swizzled)
    float v;
    if (unit < 3)       v = msgl_W[unit * 4096 + i * 64 + o];
    else if (unit < 5)  v = merge_W0[((unit - 3) * 64 + i) * 64 + o];
    else if (unit < 7)  v = merge_Wr[(unit - 5) * 4096 + i * 64 + o];
    else                v = msgc_W[(unit - 7) * 4096 + i * 64 + o];
    wT[gid] = f2bf(v);
}

// -------- CSR build --------
__global__ __launch_bounds__(256) void csr_hist(const int* __restrict__ lit_idx,
                                                int* __restrict__ cnt)
{
    int e = blockIdx.x * 256 + threadIdx.x;
    if (e < EDGES) atomicAdd(&cnt[lit_idx[e]], 1);
}

__global__ __launch_bounds__(256) void scan1(const int* __restrict__ cnt,
                                             int* __restrict__ bsum)
{
    __shared__ int red[4];
    int i = blockIdx.x * 256 + threadIdx.x;
    int s = (i < NLIT) ? cnt[i] : 0;
#pragma unroll
    for (int off = 1; off < 64; off <<= 1) s += __shfl_xor(s, off, 64);
    if ((threadIdx.x & 63) == 0) red[threadIdx.x >> 6] = s;
    __syncthreads();
    if (threadIdx.x == 0) bsum[blockIdx.x] = red[0] + red[1] + red[2] + red[3];
}

__global__ __launch_bounds__(256) void scan2(const int* __restrict__ bsum,
                                             int* __restrict__ bbase)
{
    __shared__ int tmp[256];
    int t = threadIdx.x;
    int v = (t < SCAN_BLOCKS) ? bsum[t] : 0;
    tmp[t] = v;
    __syncthreads();
#pragma unroll
    for (int off = 1; off < 256; off <<= 1) {
        int add = (t >= off) ? tmp[t - off] : 0;
        __syncthreads();
        tmp[t] += add;
        __syncthreads();
    }
    if (t < SCAN_BLOCKS) bbase[t] = tmp[t] - v;   // exclusive
}

__global__ __launch_bounds__(256) void scan3(const int* __restrict__ cnt,
                                             const int* __restrict__ bbase,
                                             int* __restrict__ off,
                                             int* __restrict__ cursor)
{
    __shared__ int tmp[256];
    int t = threadIdx.x;
    int i = blockIdx.x * 256 + t;
    int v = (i < NLIT) ? cnt[i] : 0;
    tmp[t] = v;
    __syncthreads();
#pragma unroll
    for (int offs = 1; offs < 256; offs <<= 1) {
        int add = (t >= offs) ? tmp[t - offs] : 0;
        __syncthreads();
        tmp[t] += add;
        __syncthreads();
    }
    if (i < NLIT) {
        int ex = bbase[blockIdx.x] + tmp[t] - v;
        off[i] = ex; cursor[i] = ex;
    }
    if (i == NLIT - 1) off[NLIT] = EDGES;
}

__global__ __launch_bounds__(256) void csr_scatter(const int* __restrict__ lit_idx,
                                                   int* __restrict__ cursor,
                                                   int* __restrict__ eidx)
{
    int e = blockIdx.x * 256 + threadIdx.x;
    if (e >= EDGES) return;
    int pos = atomicAdd(&cursor[lit_idx[e]], 1);
    eidx[pos] = e;
}

// -------- gather aggregation (bf16 output), group-of-4 latency breaking --------
__global__ __launch_bounds__(256) void aggregate(const unsigned short* __restrict__ h_c2l,
                                                 const int* __restrict__ off,
                                                 const int* __restrict__ eidx,
                                                 unsigned short* __restrict__ agg)
{
    int t = threadIdx.x;
    int lane8 = t & 7;
    int lit = blockIdx.x * 32 + (t >> 3);
    if (lit >= NLIT) return;
    int lo = off[lit], hi = off[lit + 1];
    float s[8] = {0, 0, 0, 0, 0, 0, 0, 0};
    int i = lo;
    for (; i + 4 <= hi; i += 4) {
        int e0 = eidx[i], e1 = eidx[i + 1], e2 = eidx[i + 2], e3 = eidx[i + 3];
        u16x8 v0 = *(const u16x8*)(h_c2l + e0 * 64 + lane8 * 8);
        u16x8 v1 = *(const u16x8*)(h_c2l + e1 * 64 + lane8 * 8);
        u16x8 v2 = *(const u16x8*)(h_c2l + e2 * 64 + lane8 * 8);
        u16x8 v3 = *(const u16x8*)(h_c2l + e3 * 64 + lane8 * 8);
#pragma unroll
        for (int j = 0; j < 8; ++j)
            s[j] += (bf2f(v0[j]) + bf2f(v1[j])) + (bf2f(v2[j]) + bf2f(v3[j]));
    }
    for (; i < hi; ++i) {
        int e = eidx[i];
        u16x8 hv = *(const u16x8*)(h_c2l + e * 64 + lane8 * 8);
#pragma unroll
        for (int j = 0; j < 8; ++j) s[j] += bf2f(hv[j]);
    }
    u16x8 o;
#pragma unroll
    for (int j = 0; j < 8; ++j) o[j] = f2bf(s[j]);
    *(u16x8*)(agg + lit * 64 + lane8 * 8) = o;
}

// -------- init: h = feat @ W_init + b  (bf16) --------
__global__ __launch_bounds__(256) void init_kernel(
    const float* __restrict__ feat_l2c, const float* __restrict__ feat_c2l,
    const float* __restrict__ W_l2c, const float* __restrict__ b_l2c,
    const float* __restrict__ W_c2l, const float* __restrict__ b_c2l,
    unsigned short* __restrict__ h_l2c, unsigned short* __restrict__ h_c2l)
{
    int gid = blockIdx.x * 256 + threadIdx.x;
    if (gid >= EDGES * 8) return;
    int e = gid >> 3, fo = (gid & 7) << 3;
    float2 fl = *(const float2*)(feat_l2c + e * 2);
    float2 fc = *(const float2*)(feat_c2l + e * 2);

    u16x8 outl, outc;
#pragma unroll
    for (int j = 0; j < 8; ++j) {
        float wl0 = W_l2c[fo + j], wl1 = W_l2c[64 + fo + j];
        float wc0 = W_c2l[fo + j], wc1 = W_c2l[64 + fo + j];
        float vl = fl.x * wl0 + fl.y * wl1 + b_l2c[fo + j];
        float vc = fc.x * wc0 + fc.y * wc1 + b_c2l[fo + j];
        outl[j] = f2bf(vl);
        outc[j] = f2bf(vc);
    }
    *(u16x8*)(h_l2c + e * 64 + fo) = outl;
    *(u16x8*)(h_c2l + e * 64 + fo) = outc;
}

// -------- FUSED literal+clause update --------
// Phase 1: lit MLP (7 layers) -> new h_l2c (global store + keep in regs)
// Phase 2: overwrite dead lit-weight LDS with clause weights + exchange tile
// Phase 3: clause MLP for clauses fully inside the block (siblings from LDS)
__global__ __launch_bounds__(512, 4) void lit_cls(
    unsigned short* __restrict__ h_c2l,
    unsigned short* __restrict__ h_l2c,
    const unsigned short* __restrict__ agg,
    const int* __restrict__ lit_idx,
    const unsigned short* __restrict__ wT,
    const float* __restrict__ msgl_b,
    const float* __restrict__ merge_b0,
    const float* __restrict__ merge_br,
    const float* __restrict__ msgc_b)
{
    __shared__ __align__(16) char lds[LIT_WBYTES + 384 * 4];   // 58880 B -> 2 blocks/CU
    int tid = threadIdx.x;
#pragma unroll
    for (int c = 0; c < 7; ++c) {
        int idx = c * 512 + tid;
        *(u16x8*)(lds + idx * 16) = *(const u16x8*)(wT + idx * 8);
    }
    float* ldsBias = (float*)(lds + LIT_WBYTES);
    if (tid < 384) {
        float v;
        if (tid < 192)      v = msgl_b[tid];
        else if (tid < 256) v = merge_b0[tid - 192];
        else                v = merge_br[tid - 256];
        ldsBias[tid] = v;
    }
    __syncthreads();

    int wv = tid >> 6, lane = tid & 63;
    int eL = lane & 31, hi = lane >> 5;
    int bpidx = (lane ^ 32) << 2;
    int block_base = blockIdx.x * EPB2;
    int block_end = block_base + EPB2; if (block_end > EDGES) block_end = EDGES;
    int base = block_base + wv * 32;
    bool active = base < EDGES;
    int e = base + eL;

    f32x16 acc[2];
    s16x8 bf[4];

    if (active) {
        int lit = lit_idx[e];

        s16x8 hfrag[4];
#pragma unroll
        for (int k = 0; k < 4; ++k)
            hfrag[k] = *(const s16x8*)(h_l2c + e * 64 + 16 * k + 8 * hi);

        s16x8 binp[4];
#pragma unroll
        for (int k = 0; k < 4; ++k) {
            int f0 = 16 * k + 8 * hi;
            u16x8 ag = *(const u16x8*)(agg + lit * 64 + f0);
            u16x8 hv = *(const u16x8*)(h_c2l + e * 64 + f0);
            s16x8 b;
#pragma unroll
            for (int j = 0; j < 8; ++j)
                b[j] = (short)f2bf((bf2f(ag[j]) - bf2f(hv[j])) * 0.125f);
            binp[k] = b;
        }

        layer32(lds,            ldsBias,       binp, acc, eL, hi);
        relayout32<true >(acc, bf, bpidx, hi);
        layer32(lds + 8192,     ldsBias + 64,  bf, acc, eL, hi);
        relayout32<true >(acc, bf, bpidx, hi);
        layer32(lds + 2 * 8192, ldsBias + 128, bf, acc, eL, hi);
        relayout32<false>(acc, bf, bpidx, hi);        // m fragments

#pragma unroll
        for (int t = 0; t < 2; ++t)
#pragma unroll
            for (int g = 0; g < 4; ++g) {
                f32x4 bv = *(const f32x4*)(ldsBias + 192 + 32 * t + 8 * g + 4 * hi);
#pragma unroll
                for (int r = 0; r < 4; ++r) acc[t][4 * g + r] = bv[r];
            }
#pragma unroll
        for (int kb = 0; kb < 8; ++kb) {
            const char* ub = lds + (3 + (kb >> 2)) * 8192;
            s16x8 bop = (kb < 4) ? bf[kb] : hfrag[kb - 4];
#pragma unroll
            for (int t = 0; t < 2; ++t) {
                int row = 32 * t + eL;
                s16x8 a = *(const s16x8*)(ub + row * 128 +
                                          ((32 * (kb & 3) + 16 * hi) ^ ((row & 7) << 4)));
                acc[t] = mfma32(a, bop, acc[t]);
            }
        }
        relayout32<true>(acc, bf, bpidx, hi);
        layer32(lds + 5 * 8192, ldsBias + 256, bf, acc, eL, hi);
        relayout32<true>(acc, bf, bpidx, hi);
        layer32(lds + 6 * 8192, ldsBias + 320, bf, acc, eL, hi);

        store32(acc, h_l2c + e * 64, hi);   // acc = new h_l2c, kept for exchange
    }
    __syncthreads();   // all phase-1 LDS reads complete

    // ---- phase 2: clause weights into [0,24576); exchange tile at [24576,57344) ----
#pragma unroll
    for (int c = 0; c < 3; ++c) {
        int idx = c * 512 + tid;
        *(u16x8*)(lds + idx * 16) = *(const u16x8*)(wT + WT_CLS_ELEM + idx * 8);
    }
    if (tid < 192) ldsBias[tid] = msgc_b[tid];
    if (active) {
        char* exch = lds + CLS_WBYTES;
        int row = wv * 32 + eL;
        int sw = (row & 7) << 4;
#pragma unroll
        for (int t = 0; t < 2; ++t)
#pragma unroll
            for (int g = 0; g < 4; ++g) {
                u16x4 p;
#pragma unroll
                for (int r = 0; r < 4; ++r) p[r] = f2bf(acc[t][4 * g + r]);
                *(u16x4*)(exch + row * 128 + ((64 * t + 16 * g + 8 * hi) ^ sw)) = p;
            }
    }
    __syncthreads();

    // ---- phase 3: clause MLP for interior clauses ----
    if (active) {
        int c3 = (e / 3) * 3;
        int d = e - c3;
        bool interior = (c3 >= block_base) && (c3 + 3 <= block_end);
        int e1 = c3 + (d == 0 ? 1 : 0);
        int e2 = c3 + (d == 2 ? 1 : 2);
        int r1 = interior ? (e1 - block_base) : 0;
        int r2 = interior ? (e2 - block_base) : 0;
        const char* exch = lds + CLS_WBYTES;

        s16x8 binp[4];
#pragma unroll
        for (int k = 0; k < 4; ++k) {
            int off = 32 * k + 16 * hi;
            u16x8 h1 = *(const u16x8*)(exch + r1 * 128 + (off ^ ((r1 & 7) << 4)));
            u16x8 h2 = *(const u16x8*)(exch + r2 * 128 + (off ^ ((r2 & 7) << 4)));
            s16x8 b;
#pragma unroll
            for (int j = 0; j < 8; ++j)
                b[j] = (short)f2bf((bf2f(h1[j]) + bf2f(h2[j])) * 0.125f);
            binp[k] = b;
        }

        layer32(lds,            ldsBias,       binp, acc, eL, hi);
        relayout32<true>(acc, bf, bpidx, hi);
        layer32(lds + 8192,     ldsBias + 64,  bf, acc, eL, hi);
        relayout32<true>(acc, bf, bpidx, hi);
        layer32(lds + 2 * 8192, ldsBias + 128, bf, acc, eL, hi);

        if (interior) store32(acc, h_c2l + e * 64, hi);
    }
}

// -------- fixup: clauses straddling a 256-edge block boundary --------
// one wave per boundary b=1..GRID_EDGE-1; covers edges [256b-16, 256b+16)
__global__ __launch_bounds__(64) void cls_fixup(
    const unsigned short* __restrict__ h_l2c,
    unsigned short* __restrict__ h_c2l,
    const unsigned short* __restrict__ wT,
    const float* __restrict__ msgc_b)
{
    int boundary = (blockIdx.x + 1) * EPB2;
    int lane = threadIdx.x;
    int eL = lane & 31, hi = lane >> 5;
    int bpidx = (lane ^ 32) << 2;
    int e = boundary - 16 + eL;

    int c3 = (e / 3) * 3;
    int d = e - c3;
    bool work = (c3 < boundary) && (c3 + 3 > boundary);
    if (__ballot(work) == 0ULL) return;   // boundary divisible by 3: no straddle

    int e1 = c3 + (d == 0 ? 1 : 0);
    int e2 = c3 + (d == 2 ? 1 : 2);

    s16x8 binp[4];
#pragma unroll
    for (int k = 0; k < 4; ++k) {
        int f0 = 16 * k + 8 * hi;
        u16x8 h1 = *(const u16x8*)(h_l2c + e1 * 64 + f0);
        u16x8 h2 = *(const u16x8*)(h_l2c + e2 * 64 + f0);
        s16x8 b;
#pragma unroll
        for (int j = 0; j < 8; ++j)
            b[j] = (short)f2bf((bf2f(h1[j]) + bf2f(h2[j])) * 0.125f);
        binp[k] = b;
    }

    f32x16 acc[2];
    s16x8 bf[4];
    layer32g(wT + WT_CLS_ELEM,            msgc_b,       binp, acc, eL, hi);
    relayout32<true>(acc, bf, bpidx, hi);
    layer32g(wT + WT_CLS_ELEM + 4096,     msgc_b + 64,  bf, acc, eL, hi);
    relayout32<true>(acc, bf, bpidx, hi);
    layer32g(wT + WT_CLS_ELEM + 2 * 4096, msgc_b + 128, bf, acc, eL, hi);

    if (work) store32(acc, h_c2l + e * 64, hi);
}

// -------- readout stage 1: per-graph sum of h_c2l over contiguous 75000 edges --------
__global__ __launch_bounds__(256) void readout_sum(
    const unsigned short* __restrict__ h_c2l, float* __restrict__ ro_acc)
{
    __shared__ float lsum[32][64];
    int g = blockIdx.x >> 6, chunk = blockIdx.x & 63;
    int t = threadIdx.x;
    int fg = t & 7, el = t >> 3;
    float s[8] = {0, 0, 0, 0, 0, 0, 0, 0};
    for (int idx = chunk * 32 + el; idx < EPG; idx += 2048) {
        u16x8 hv = *(const u16x8*)(h_c2l + (g * EPG + idx) * 64 + fg * 8);
#pragma unroll
        for (int j = 0; j < 8; ++j) s[j] += bf2f(hv[j]);
    }
#pragma unroll
    for (int j = 0; j < 8; ++j) lsum[el][fg * 8 + j] = s[j];
    __syncthreads();
    if (t < 64) {
        float tot = 0.f;
#pragma unroll 8
        for (int r = 0; r < 32; ++r) tot += lsum[r][t];
        atomicAdd(&ro_acc[g * 64 + t], tot);
    }
}

// -------- readout stage 2: tiny MLP + sigmoid --------
__global__ __launch_bounds__(256) void readout_mlp(
    const float* __restrict__ ro_acc, const float* __restrict__ ro_W,
    const float* __restrict__ ro_b, const float* __restrict__ ro_W2,
    const float* __restrict__ ro_b2, float* __restrict__ out)
{
    __shared__ float xb[NGRAPH][HDIM];
    __shared__ float yb[NGRAPH][HDIM];
    int g = threadIdx.x >> 6;
    int j = threadIdx.x & 63;
    xb[g][j] = ro_acc[g * HDIM + j] * (1.0f / 12500.0f);
    __syncthreads();
    float a = ro_b[j];
#pragma unroll 8
    for (int k = 0; k < HDIM; ++k) a += xb[g][k] * ro_W[k * HDIM + j];
    a = fmaxf(a, 0.0f);
    yb[g][j] = a;
    __syncthreads();
    float a2 = ro_b[HDIM + j];
#pragma unroll 8
    for (int k = 0; k < HDIM; ++k) a2 += yb[g][k] * ro_W[4096 + k * HDIM + j];
    a2 = fmaxf(a2, 0.0f);
    float p = a2 * ro_W2[j];
#pragma unroll
    for (int off = 32; off > 0; off >>= 1) p += __shfl_down(p, off, 64);
    if (j == 0) out[g] = 1.0f / (1.0f + expf(-(p + ro_b2[0])));
}

extern "C" void kernel_launch(void* const* d_in, const int* in_sizes, int n_in,
                              void* d_out, int out_size, void* d_ws, size_t ws_size,
                              hipStream_t stream)
{
    const float* feat_l2c = (const float*)d_in[0];
    const float* feat_c2l = (const float*)d_in[1];
    const int*   lit_idx  = (const int*)d_in[2];
    // d_in[3] (cls_idx) unused: edges are clause-major by construction
    const float* W_l2c    = (const float*)d_in[4];
    const float* b_l2c    = (const float*)d_in[5];
    const float* W_c2l    = (const float*)d_in[6];
    const float* b_c2l    = (const float*)d_in[7];
    const float* msgl_W   = (const float*)d_in[8];
    const float* msgl_b   = (const float*)d_in[9];
    const float* merge_W0 = (const float*)d_in[10];
    const float* merge_b0 = (const float*)d_in[11];
    const float* merge_Wr = (const float*)d_in[12];
    const float* merge_br = (const float*)d_in[13];
    const float* msgc_W   = (const float*)d_in[14];
    const float* msgc_b   = (const float*)d_in[15];
    const float* ro_W     = (const float*)d_in[16];
    const float* ro_b     = (const float*)d_in[17];
    const float* ro_W2    = (const float*)d_in[18];
    const float* ro_b2    = (const float*)d_in[19];

    char* ws = (char*)d_ws;
    unsigned short* h_l2c  = (unsigned short*)(ws + OFF_HL2C);
    unsigned short* h_c2l  = (unsigned short*)(ws + OFF_HC2L);
    unsigned short* agg    = (unsigned short*)(ws + OFF_AGG);
    unsigned short* wT     = (unsigned short*)(ws + OFF_WT);
    float*          ro_acc = (float*)(ws + OFF_ROACC);
    int*            cnt    = (int*)(ws + OFF_CNT);
    int*            csroff = (int*)(ws + OFF_CSROFF);
    int*            cursor = (int*)(ws + OFF_CURSOR);
    int*            eidx   = (int*)(ws + OFF_EIDX);
    int*            bsum   = (int*)(ws + OFF_BSUM);
    int*            bbase  = (int*)(ws + OFF_BBASE);

    hipMemsetAsync(cnt, 0, NLIT * sizeof(int), stream);
    hipMemsetAsync(ro_acc, 0, NGRAPH * 64 * sizeof(float), stream);

    prep_weights<<<(WT_TOTAL + 255) / 256, 256, 0, stream>>>(msgl_W, merge_W0, merge_Wr, msgc_W, wT);

    // CSR of lit_idx (per-launch rebuild; 3-stage parallel scan)
    csr_hist<<<(EDGES + 255) / 256, 256, 0, stream>>>(lit_idx, cnt);
    scan1<<<SCAN_BLOCKS, 256, 0, stream>>>(cnt, bsum);
    scan2<<<1, 256, 0, stream>>>(bsum, bbase);
    scan3<<<SCAN_BLOCKS, 256, 0, stream>>>(cnt, bbase, csroff, cursor);
    csr_scatter<<<(EDGES + 255) / 256, 256, 0, stream>>>(lit_idx, cursor, eidx);

    init_kernel<<<EDGES * 8 / 256, 256, 0, stream>>>(feat_l2c, feat_c2l, W_l2c, b_l2c,
                                                     W_c2l, b_c2l, h_l2c, h_c2l);
    for (int r = 0; r < 3; ++r) {
        aggregate<<<(NLIT + 31) / 32, 256, 0, stream>>>(h_c2l, csroff, eidx, agg);
        lit_cls<<<GRID_EDGE, 512, 0, stream>>>(h_c2l, h_l2c, agg, lit_idx, wT,
                                               msgl_b, merge_b0, merge_br, msgc_b);
        cls_fixup<<<GRID_EDGE - 1, 64, 0, stream>>>(h_l2c, h_c2l, wT, msgc_b);
    }
    readout_sum<<<256, 256, 0, stream>>>(h_c2l, ro_acc);
    readout_mlp<<<1, 256, 0, stream>>>(ro_acc, ro_W, ro_b, ro_W2, ro_b2, (float*)d_out);
}

// Round 13
// 311.489 us; speedup vs baseline: 1.0564x; 1.0564x over previous
//
#include <hip/hip_runtime.h>
#include <hip/hip_bf16.h>
#include <stdint.h>

// ---------------- problem constants ----------------
#define EDGES   300000
#define NLIT    50000
#define NGRAPH  4
#define EPG     75000          // edges per graph (contiguous)
#define HDIM    64

// ws layout (bytes)
#define OFF_HL2C   0
#define OFF_HC2L   38400000
#define OFF_AGG    76800000
#define OFF_WT     89600000
#define OFF_ROACC  89681920
#define OFF_CNT    89682944
#define OFF_CSROFF 89882944
#define OFF_CURSOR 90082948
#define OFF_EIDX   90282948
#define OFF_BSUM   91482948
#define OFF_BBASE  91484000

// wT global layout: 10 "units", each [64 rows=out][64 cols=in] bf16 (4096 elems),
// stored PRE-SWIZZLED: element (u,row,col) at u*4096 + row*64 + (col ^ ((row&7)<<3)).
// u0-2: msglT ; u3: merge0T cols 0-63 (m part) ; u4: merge0T cols 64-127 (h part)
// u5-6: mergeRT ; u7-9: msgcT
#define WT_TOTAL    40960
#define WT_CLS_ELEM 28672      // element offset of clause units (u7)

#define LIT_WBYTES (7 * 8192)   // 57344
#define CLS_WBYTES (3 * 8192)   // 24576
#define EPB2       256          // edges per block (8 waves x 32)
#define GRID_EDGE  ((EDGES + EPB2 - 1) / EPB2)   // 1172

#define SCAN_BLOCKS ((NLIT + 255) / 256)   // 196

typedef __attribute__((ext_vector_type(8)))  short          s16x8;
typedef __attribute__((ext_vector_type(8)))  unsigned short u16x8;
typedef __attribute__((ext_vector_type(4)))  unsigned short u16x4;
typedef __attribute__((ext_vector_type(4)))  float          f32x4;
typedef __attribute__((ext_vector_type(16))) float          f32x16;

__device__ __forceinline__ f32x16 mfma32(s16x8 a, s16x8 b, f32x16 c) {
    return __builtin_amdgcn_mfma_f32_32x32x16_bf16(a, b, c, 0, 0, 0);
}
__device__ __forceinline__ float bf2f(unsigned short s) {
    union { unsigned int u; float f; } v; v.u = ((unsigned int)s) << 16; return v.f;
}
// native RNE convert (compiler emits v_cvt_pk_bf16_f32 for pairs)
__device__ __forceinline__ unsigned short f2bf(float f) {
    union { __hip_bfloat16 b; unsigned short s; } v;
    v.b = __float2bfloat16(f);
    return v.s;
}
__device__ __forceinline__ unsigned pk2(float a, float b) {
    return (unsigned)f2bf(a) | ((unsigned)f2bf(b) << 16);
}

// in-register C->B relayout, 2 bpermutes/kb (select-before-permute), HW-verified
template<bool RELU>
__device__ __forceinline__ void relayout32(f32x16 (&acc)[2], s16x8 (&bout)[4],
                                           int bpidx, int hi)
{
    if (RELU) {
#pragma unroll
        for (int t = 0; t < 2; ++t)
#pragma unroll
            for (int i = 0; i < 16; ++i) acc[t][i] = fmaxf(acc[t][i], 0.f);
    }
#pragma unroll
    for (int kb = 0; kb < 4; ++kb) {
        int m0 = 2 * kb, m1 = 2 * kb + 1;
        int t0 = m0 >> 2, g0 = m0 & 3, t1 = m1 >> 2, g1 = m1 & 3;
        unsigned A0 = pk2(acc[t0][4 * g0 + 0], acc[t0][4 * g0 + 1]);
        unsigned A1 = pk2(acc[t0][4 * g0 + 2], acc[t0][4 * g0 + 3]);
        unsigned B0 = pk2(acc[t1][4 * g1 + 0], acc[t1][4 * g1 + 1]);
        unsigned B1 = pk2(acc[t1][4 * g1 + 2], acc[t1][4 * g1 + 3]);
        unsigned s0 = hi ? A0 : B0;
        unsigned s1 = hi ? A1 : B1;
        unsigned p0 = (unsigned)__builtin_amdgcn_ds_bpermute(bpidx, (int)s0);
        unsigned p1 = (unsigned)__builtin_amdgcn_ds_bpermute(bpidx, (int)s1);
        union { unsigned w[4]; s16x8 v; } u;
        u.w[0] = hi ? p0 : A0;
        u.w[1] = hi ? p1 : A1;
        u.w[2] = hi ? B0 : p0;
        u.w[3] = hi ? B1 : p1;
        bout[kb] = u.v;
    }
}

__device__ __forceinline__ void store32(const f32x16 (&acc)[2],
                                        unsigned short* __restrict__ dst, int hi)
{
#pragma unroll
    for (int t = 0; t < 2; ++t)
#pragma unroll
        for (int g = 0; g < 4; ++g) {
            u16x4 p;
#pragma unroll
            for (int r = 0; r < 4; ++r) p[r] = f2bf(acc[t][4 * g + r]);
            *(u16x4*)(dst + 32 * t + 8 * g + 4 * hi) = p;
        }
}

// one 64->64 layer, 32x32x16 MFMA, weights in swizzled LDS unit, bias in LDS
__device__ __forceinline__ void layer32(const char* __restrict__ unitBase,
                                        const float* __restrict__ biasL,
                                        const s16x8 (&bin)[4], f32x16 (&acc)[2],
                                        int eL, int hi)
{
#pragma unroll
    for (int t = 0; t < 2; ++t)
#pragma unroll
        for (int g = 0; g < 4; ++g) {
            f32x4 bv = *(const f32x4*)(biasL + 32 * t + 8 * g + 4 * hi);
#pragma unroll
            for (int r = 0; r < 4; ++r) acc[t][4 * g + r] = bv[r];
        }
#pragma unroll
    for (int kb = 0; kb < 4; ++kb)
#pragma unroll
        for (int t = 0; t < 2; ++t) {
            int row = 32 * t + eL;
            s16x8 a = *(const s16x8*)(unitBase + row * 128 +
                                      ((32 * kb + 16 * hi) ^ ((row & 7) << 4)));
            acc[t] = mfma32(a, bin[kb], acc[t]);
        }
}

// -------- transpose + bf16 + PRE-SWIZZLE all round weights into unit layout --------
__global__ __launch_bounds__(256) void prep_weights(
    const float* __restrict__ msgl_W, const float* __restrict__ merge_W0,
    const float* __restrict__ merge_Wr, const float* __restrict__ msgc_W,
    unsigned short* __restrict__ wT)
{
    int gid = blockIdx.x * 256 + threadIdx.x;
    if (gid >= WT_TOTAL) return;
    int unit = gid >> 12;
    int o = (gid >> 6) & 63;              // row = out
    int csw = gid & 63;
    int i = csw ^ ((o & 7) << 3);         // col = in (un-swizzled)
    float v;
    if (unit < 3)       v = msgl_W[unit * 4096 + i * 64 + o];
    else if (unit < 5)  v = merge_W0[((unit - 3) * 64 + i) * 64 + o];
    else if (unit < 7)  v = merge_Wr[(unit - 5) * 4096 + i * 64 + o];
    else                v = msgc_W[(unit - 7) * 4096 + i * 64 + o];
    wT[gid] = f2bf(v);
}

// -------- CSR build: histogram -> 3-stage parallel scan -> scatter --------
__global__ __launch_bounds__(256) void csr_hist(const int* __restrict__ lit_idx,
                                                int* __restrict__ cnt)
{
    int e = blockIdx.x * 256 + threadIdx.x;
    if (e < EDGES) atomicAdd(&cnt[lit_idx[e]], 1);
}

__global__ __launch_bounds__(256) void scan1(const int* __restrict__ cnt,
                                             int* __restrict__ bsum)
{
    __shared__ int red[4];
    int i = blockIdx.x * 256 + threadIdx.x;
    int s = (i < NLIT) ? cnt[i] : 0;
#pragma unroll
    for (int off = 1; off < 64; off <<= 1) s += __shfl_xor(s, off, 64);
    if ((threadIdx.x & 63) == 0) red[threadIdx.x >> 6] = s;
    __syncthreads();
    if (threadIdx.x == 0) bsum[blockIdx.x] = red[0] + red[1] + red[2] + red[3];
}

__global__ __launch_bounds__(256) void scan2(const int* __restrict__ bsum,
                                             int* __restrict__ bbase)
{
    __shared__ int tmp[256];
    int t = threadIdx.x;
    int v = (t < SCAN_BLOCKS) ? bsum[t] : 0;
    tmp[t] = v;
    __syncthreads();
#pragma unroll
    for (int off = 1; off < 256; off <<= 1) {
        int add = (t >= off) ? tmp[t - off] : 0;
        __syncthreads();
        tmp[t] += add;
        __syncthreads();
    }
    if (t < SCAN_BLOCKS) bbase[t] = tmp[t] - v;   // exclusive
}

__global__ __launch_bounds__(256) void scan3(const int* __restrict__ cnt,
                                             const int* __restrict__ bbase,
                                             int* __restrict__ off,
                                             int* __restrict__ cursor)
{
    __shared__ int tmp[256];
    int t = threadIdx.x;
    int i = blockIdx.x * 256 + t;
    int v = (i < NLIT) ? cnt[i] : 0;
    tmp[t] = v;
    __syncthreads();
#pragma unroll
    for (int offs = 1; offs < 256; offs <<= 1) {
        int add = (t >= offs) ? tmp[t - offs] : 0;
        __syncthreads();
        tmp[t] += add;
        __syncthreads();
    }
    if (i < NLIT) {
        int ex = bbase[blockIdx.x] + tmp[t] - v;
        off[i] = ex; cursor[i] = ex;
    }
    if (i == NLIT - 1) off[NLIT] = EDGES;
}

__global__ __launch_bounds__(256) void csr_scatter(const int* __restrict__ lit_idx,
                                                   int* __restrict__ cursor,
                                                   int* __restrict__ eidx)
{
    int e = blockIdx.x * 256 + threadIdx.x;
    if (e >= EDGES) return;
    int pos = atomicAdd(&cursor[lit_idx[e]], 1);
    eidx[pos] = e;
}

// -------- gather aggregation (bf16 output), group-of-4 latency breaking --------
__global__ __launch_bounds__(256) void aggregate(const unsigned short* __restrict__ h_c2l,
                                                 const int* __restrict__ off,
                                                 const int* __restrict__ eidx,
                                                 unsigned short* __restrict__ agg)
{
    int t = threadIdx.x;
    int lane8 = t & 7;
    int lit = blockIdx.x * 32 + (t >> 3);
    if (lit >= NLIT) return;
    int lo = off[lit], hi = off[lit + 1];
    float s[8] = {0, 0, 0, 0, 0, 0, 0, 0};
    int i = lo;
    for (; i + 4 <= hi; i += 4) {
        int e0 = eidx[i], e1 = eidx[i + 1], e2 = eidx[i + 2], e3 = eidx[i + 3];
        u16x8 v0 = *(const u16x8*)(h_c2l + e0 * 64 + lane8 * 8);
        u16x8 v1 = *(const u16x8*)(h_c2l + e1 * 64 + lane8 * 8);
        u16x8 v2 = *(const u16x8*)(h_c2l + e2 * 64 + lane8 * 8);
        u16x8 v3 = *(const u16x8*)(h_c2l + e3 * 64 + lane8 * 8);
#pragma unroll
        for (int j = 0; j < 8; ++j)
            s[j] += (bf2f(v0[j]) + bf2f(v1[j])) + (bf2f(v2[j]) + bf2f(v3[j]));
    }
    for (; i < hi; ++i) {
        int e = eidx[i];
        u16x8 hv = *(const u16x8*)(h_c2l + e * 64 + lane8 * 8);
#pragma unroll
        for (int j = 0; j < 8; ++j) s[j] += bf2f(hv[j]);
    }
    u16x8 o;
#pragma unroll
    for (int j = 0; j < 8; ++j) o[j] = f2bf(s[j]);
    *(u16x8*)(agg + lit * 64 + lane8 * 8) = o;
}

// -------- init: h = feat @ W_init + b  (bf16) --------
__global__ __launch_bounds__(256) void init_kernel(
    const float* __restrict__ feat_l2c, const float* __restrict__ feat_c2l,
    const float* __restrict__ W_l2c, const float* __restrict__ b_l2c,
    const float* __restrict__ W_c2l, const float* __restrict__ b_c2l,
    unsigned short* __restrict__ h_l2c, unsigned short* __restrict__ h_c2l)
{
    int gid = blockIdx.x * 256 + threadIdx.x;
    if (gid >= EDGES * 8) return;
    int e = gid >> 3, fo = (gid & 7) << 3;
    float2 fl = *(const float2*)(feat_l2c + e * 2);
    float2 fc = *(const float2*)(feat_c2l + e * 2);

    u16x8 outl, outc;
#pragma unroll
    for (int j = 0; j < 8; ++j) {
        float wl0 = W_l2c[fo + j], wl1 = W_l2c[64 + fo + j];
        float wc0 = W_c2l[fo + j], wc1 = W_c2l[64 + fo + j];
        float vl = fl.x * wl0 + fl.y * wl1 + b_l2c[fo + j];
        float vc = fc.x * wc0 + fc.y * wc1 + b_c2l[fo + j];
        outl[j] = f2bf(vl);
        outc[j] = f2bf(vc);
    }
    *(u16x8*)(h_l2c + e * 64 + fo) = outl;
    *(u16x8*)(h_c2l + e * 64 + fo) = outc;
}

// -------- literal update (R5 structure; bf16 agg): x0=(agg-h)/8 -> MLP3 -> merge --------
__global__ __launch_bounds__(512, 4) void lit_update(
    const unsigned short* __restrict__ h_c2l,
    unsigned short* __restrict__ h_l2c,
    const unsigned short* __restrict__ agg,
    const int* __restrict__ lit_idx,
    const unsigned short* __restrict__ wT,
    const float* __restrict__ msgl_b,
    const float* __restrict__ merge_b0,
    const float* __restrict__ merge_br)
{
    __shared__ __align__(16) char lds[LIT_WBYTES + 384 * 4];   // 58880 B -> 2 blocks/CU
    int tid = threadIdx.x;
#pragma unroll
    for (int c = 0; c < 7; ++c) {
        int idx = c * 512 + tid;
        *(u16x8*)(lds + idx * 16) = *(const u16x8*)(wT + idx * 8);
    }
    float* ldsBias = (float*)(lds + LIT_WBYTES);
    if (tid < 384) {
        float v;
        if (tid < 192)      v = msgl_b[tid];
        else if (tid < 256) v = merge_b0[tid - 192];
        else                v = merge_br[tid - 256];
        ldsBias[tid] = v;
    }
    __syncthreads();

    int wv = tid >> 6, lane = tid & 63;
    int eL = lane & 31, hi = lane >> 5;
    int bpidx = (lane ^ 32) << 2;
    int base = blockIdx.x * EPB2 + wv * 32;
    if (base >= EDGES) return;
    int e = base + eL;
    int lit = lit_idx[e];

    // old h_l2c fragments (merge kb 4-7) -- load early, hide under msgl layers
    s16x8 hfrag[4];
#pragma unroll
    for (int k = 0; k < 4; ++k)
        hfrag[k] = *(const s16x8*)(h_l2c + e * 64 + 16 * k + 8 * hi);

    // input x0 fragments (agg is bf16)
    s16x8 binp[4];
#pragma unroll
    for (int k = 0; k < 4; ++k) {
        int f0 = 16 * k + 8 * hi;
        u16x8 ag = *(const u16x8*)(agg + lit * 64 + f0);
        u16x8 hv = *(const u16x8*)(h_c2l + e * 64 + f0);
        s16x8 b;
#pragma unroll
        for (int j = 0; j < 8; ++j)
            b[j] = (short)f2bf((bf2f(ag[j]) - bf2f(hv[j])) * 0.125f);
        binp[k] = b;
    }

    f32x16 acc[2];
    s16x8 bf[4];
    layer32(lds,            ldsBias,       binp, acc, eL, hi);
    relayout32<true >(acc, bf, bpidx, hi);
    layer32(lds + 8192,     ldsBias + 64,  bf, acc, eL, hi);
    relayout32<true >(acc, bf, bpidx, hi);
    layer32(lds + 2 * 8192, ldsBias + 128, bf, acc, eL, hi);
    relayout32<false>(acc, bf, bpidx, hi);        // m fragments

    // merge layer 0: K=128 = [m | h_old], units 3 (m) and 4 (h)
#pragma unroll
    for (int t = 0; t < 2; ++t)
#pragma unroll
        for (int g = 0; g < 4; ++g) {
            f32x4 bv = *(const f32x4*)(ldsBias + 192 + 32 * t + 8 * g + 4 * hi);
#pragma unroll
            for (int r = 0; r < 4; ++r) acc[t][4 * g + r] = bv[r];
        }
#pragma unroll
    for (int kb = 0; kb < 8; ++kb) {
        const char* ub = lds + (3 + (kb >> 2)) * 8192;
        s16x8 bop = (kb < 4) ? bf[kb] : hfrag[kb - 4];
#pragma unroll
        for (int t = 0; t < 2; ++t) {
            int row = 32 * t + eL;
            s16x8 a = *(const s16x8*)(ub + row * 128 +
                                      ((32 * (kb & 3) + 16 * hi) ^ ((row & 7) << 4)));
            acc[t] = mfma32(a, bop, acc[t]);
        }
    }
    relayout32<true>(acc, bf, bpidx, hi);
    layer32(lds + 5 * 8192, ldsBias + 256, bf, acc, eL, hi);
    relayout32<true>(acc, bf, bpidx, hi);
    layer32(lds + 6 * 8192, ldsBias + 320, bf, acc, eL, hi);

    store32(acc, h_l2c + e * 64, hi);
}

// -------- clause update: x0=(sum of 2 siblings)/8 -> MLP3 -> h_c2l --------
__global__ __launch_bounds__(512, 4) void clause_update(
    const unsigned short* __restrict__ h_l2c,
    unsigned short* __restrict__ h_c2l,
    const unsigned short* __restrict__ msgcT,
    const float* __restrict__ msgc_b)
{
    __shared__ __align__(16) char lds[CLS_WBYTES + 192 * 4];   // 25344 B
    int tid = threadIdx.x;
#pragma unroll
    for (int c = 0; c < 3; ++c) {
        int idx = c * 512 + tid;
        *(u16x8*)(lds + idx * 16) = *(const u16x8*)(msgcT + idx * 8);
    }
    float* ldsBias = (float*)(lds + CLS_WBYTES);
    if (tid < 192) ldsBias[tid] = msgc_b[tid];
    __syncthreads();

    int wv = tid >> 6, lane = tid & 63;
    int eL = lane & 31, hi = lane >> 5;
    int bpidx = (lane ^ 32) << 2;
    int base = blockIdx.x * EPB2 + wv * 32;
    if (base >= EDGES) return;
    int e = base + eL;

    int c3 = (e / 3) * 3;
    int d = e - c3;
    int e1 = c3 + (d == 0 ? 1 : 0);
    int e2 = c3 + (d == 2 ? 1 : 2);

    s16x8 binp[4];
#pragma unroll
    for (int k = 0; k < 4; ++k) {
        int f0 = 16 * k + 8 * hi;
        u16x8 h1 = *(const u16x8*)(h_l2c + e1 * 64 + f0);
        u16x8 h2 = *(const u16x8*)(h_l2c + e2 * 64 + f0);
        s16x8 b;
#pragma unroll
        for (int j = 0; j < 8; ++j)
            b[j] = (short)f2bf((bf2f(h1[j]) + bf2f(h2[j])) * 0.125f);
        binp[k] = b;
    }

    f32x16 acc[2];
    s16x8 bf[4];
    layer32(lds,            ldsBias,       binp, acc, eL, hi);
    relayout32<true>(acc, bf, bpidx, hi);
    layer32(lds + 8192,     ldsBias + 64,  bf, acc, eL, hi);
    relayout32<true>(acc, bf, bpidx, hi);
    layer32(lds + 2 * 8192, ldsBias + 128, bf, acc, eL, hi);

    store32(acc, h_c2l + e * 64, hi);
}

// -------- readout stage 1: per-graph sum of h_c2l over contiguous 75000 edges --------
__global__ __launch_bounds__(256) void readout_sum(
    const unsigned short* __restrict__ h_c2l, float* __restrict__ ro_acc)
{
    __shared__ float lsum[32][64];
    int g = blockIdx.x >> 6, chunk = blockIdx.x & 63;
    int t = threadIdx.x;
    int fg = t & 7, el = t >> 3;
    float s[8] = {0, 0, 0, 0, 0, 0, 0, 0};
    for (int idx = chunk * 32 + el; idx < EPG; idx += 2048) {
        u16x8 hv = *(const u16x8*)(h_c2l + (g * EPG + idx) * 64 + fg * 8);
#pragma unroll
        for (int j = 0; j < 8; ++j) s[j] += bf2f(hv[j]);
    }
#pragma unroll
    for (int j = 0; j < 8; ++j) lsum[el][fg * 8 + j] = s[j];
    __syncthreads();
    if (t < 64) {
        float tot = 0.f;
#pragma unroll 8
        for (int r = 0; r < 32; ++r) tot += lsum[r][t];
        atomicAdd(&ro_acc[g * 64 + t], tot);
    }
}

// -------- readout stage 2: tiny MLP + sigmoid --------
__global__ __launch_bounds__(256) void readout_mlp(
    const float* __restrict__ ro_acc, const float* __restrict__ ro_W,
    const float* __restrict__ ro_b, const float* __restrict__ ro_W2,
    const float* __restrict__ ro_b2, float* __restrict__ out)
{
    __shared__ float xb[NGRAPH][HDIM];
    __shared__ float yb[NGRAPH][HDIM];
    int g = threadIdx.x >> 6;
    int j = threadIdx.x & 63;
    xb[g][j] = ro_acc[g * HDIM + j] * (1.0f / 12500.0f);
    __syncthreads();
    float a = ro_b[j];
#pragma unroll 8
    for (int k = 0; k < HDIM; ++k) a += xb[g][k] * ro_W[k * HDIM + j];
    a = fmaxf(a, 0.0f);
    yb[g][j] = a;
    __syncthreads();
    float a2 = ro_b[HDIM + j];
#pragma unroll 8
    for (int k = 0; k < HDIM; ++k) a2 += yb[g][k] * ro_W[4096 + k * HDIM + j];
    a2 = fmaxf(a2, 0.0f);
    float p = a2 * ro_W2[j];
#pragma unroll
    for (int off = 32; off > 0; off >>= 1) p += __shfl_down(p, off, 64);
    if (j == 0) out[g] = 1.0f / (1.0f + expf(-(p + ro_b2[0])));
}

extern "C" void kernel_launch(void* const* d_in, const int* in_sizes, int n_in,
                              void* d_out, int out_size, void* d_ws, size_t ws_size,
                              hipStream_t stream)
{
    const float* feat_l2c = (const float*)d_in[0];
    const float* feat_c2l = (const float*)d_in[1];
    const int*   lit_idx  = (const int*)d_in[2];
    // d_in[3] (cls_idx) unused: edges are clause-major by construction
    const float* W_l2c    = (const float*)d_in[4];
    const float* b_l2c    = (const float*)d_in[5];
    const float* W_c2l    = (const float*)d_in[6];
    const float* b_c2l    = (const float*)d_in[7];
    const float* msgl_W   = (const float*)d_in[8];
    const float* msgl_b   = (const float*)d_in[9];
    const float* merge_W0 = (const float*)d_in[10];
    const float* merge_b0 = (const float*)d_in[11];
    const float* merge_Wr = (const float*)d_in[12];
    const float* merge_br = (const float*)d_in[13];
    const float* msgc_W   = (const float*)d_in[14];
    const float* msgc_b   = (const float*)d_in[15];
    const float* ro_W     = (const float*)d_in[16];
    const float* ro_b     = (const float*)d_in[17];
    const float* ro_W2    = (const float*)d_in[18];
    const float* ro_b2    = (const float*)d_in[19];

    char* ws = (char*)d_ws;
    unsigned short* h_l2c  = (unsigned short*)(ws + OFF_HL2C);
    unsigned short* h_c2l  = (unsigned short*)(ws + OFF_HC2L);
    unsigned short* agg    = (unsigned short*)(ws + OFF_AGG);
    unsigned short* wT     = (unsigned short*)(ws + OFF_WT);
    float*          ro_acc = (float*)(ws + OFF_ROACC);
    int*            cnt    = (int*)(ws + OFF_CNT);
    int*            csroff = (int*)(ws + OFF_CSROFF);
    int*            cursor = (int*)(ws + OFF_CURSOR);
    int*            eidx   = (int*)(ws + OFF_EIDX);
    int*            bsum   = (int*)(ws + OFF_BSUM);
    int*            bbase  = (int*)(ws + OFF_BBASE);

    hipMemsetAsync(cnt, 0, NLIT * sizeof(int), stream);
    hipMemsetAsync(ro_acc, 0, NGRAPH * 64 * sizeof(float), stream);

    prep_weights<<<(WT_TOTAL + 255) / 256, 256, 0, stream>>>(msgl_W, merge_W0, merge_Wr, msgc_W, wT);

    // CSR of lit_idx (per-launch rebuild; 3-stage parallel scan)
    csr_hist<<<(EDGES + 255) / 256, 256, 0, stream>>>(lit_idx, cnt);
    scan1<<<SCAN_BLOCKS, 256, 0, stream>>>(cnt, bsum);
    scan2<<<1, 256, 0, stream>>>(bsum, bbase);
    scan3<<<SCAN_BLOCKS, 256, 0, stream>>>(cnt, bbase, csroff, cursor);
    csr_scatter<<<(EDGES + 255) / 256, 256, 0, stream>>>(lit_idx, cursor, eidx);

    init_kernel<<<EDGES * 8 / 256, 256, 0, stream>>>(feat_l2c, feat_c2l, W_l2c, b_l2c,
                                                     W_c2l, b_c2l, h_l2c, h_c2l);
    for (int r = 0; r < 3; ++r) {
        aggregate<<<(NLIT + 31) / 32, 256, 0, stream>>>(h_c2l, csroff, eidx, agg);
        lit_update<<<GRID_EDGE, 512, 0, stream>>>(h_c2l, h_l2c, agg, lit_idx, wT,
                                                  msgl_b, merge_b0, merge_br);
        clause_update<<<GRID_EDGE, 512, 0, stream>>>(h_l2c, h_c2l, wT + WT_CLS_ELEM, msgc_b);
    }
    readout_sum<<<256, 256, 0, stream>>>(h_c2l, ro_acc);
    readout_mlp<<<1, 256, 0, stream>>>(ro_acc, ro_W, ro_b, ro_W2, ro_b2, (float*)d_out);
}